// Round 1
// baseline (135.860 us; speedup 1.0000x reference)
//
#include <hip/hip_runtime.h>

#define D 4096
#define H 512
#define NCH 64
#define CCH 64
#define B 8
#define COUT 8

// workspace layout (float offsets)
#define OFF_P     0                         // P[n][h]            64*512
#define OFF_UPART (OFF_P + NCH*H)           // upart[n][b][h]     64*8*512
#define OFF_S     (OFF_UPART + NCH*B*H)     // s[b][h]            8*512
#define OFF_ST2   (OFF_S + B*H)             // -2*t*s[b][h]       8*512
#define OFF_Q     (OFF_ST2 + B*H)           // q[b][h]            8*512
#define OFF_C     (OFF_Q + B*H)             // c[h]               512
#define OFF_VN    (OFF_C + H)               // ||v_b||+1e-6       8
#define OFF_W     (OFF_VN + 8)              // w[b][n][h]         8*64*512
#define OFF_A1    (OFF_W + B*NCH*H)         // a1[b][n][i]        8*64*64
#define OFF_Z     (OFF_A1 + B*NCH*CCH)      // z[b][n][i]         8*64*64
#define WS_FLOATS (OFF_Z + B*NCH*CCH)

__global__ void k0_zero(float* __restrict__ ws) {
    int idx = blockIdx.x * 256 + threadIdx.x;   // 32768 threads
    ws[OFF_Z + idx] = 0.f;
}

// K1: per (n-chunk, h-tile): P[n,h] = sum_k W1[n*64+k, h]; upart[n,b,h] = sum_k W1*x
__global__ void k1_reduce_w1(const float* __restrict__ W1,
                             const float* __restrict__ state,
                             const float* __restrict__ x0,
                             const float* __restrict__ x1,
                             const float* __restrict__ tptr,
                             float* __restrict__ ws) {
    int n   = blockIdx.x;          // 0..63
    int ht  = blockIdx.y;          // 0..3
    int tid = threadIdx.x;         // 0..127
    int h   = ht * 128 + tid;

    __shared__ float xs[B][64];
    float ts = tptr[0];
    float window = 4.f * ts * (1.f - ts);
    if (tid < 64) {
        int d = n * 64 + tid;
        for (int b = 0; b < B; ++b) {
            float a0 = x0[b * D + d];
            float a1v = x1[b * D + d];
            float dev = state[b * D + d];
            xs[b][tid] = a0 + ts * (a1v - a0) + window * dev;
        }
    }
    __syncthreads();

    float p = 0.f;
    float up[B];
#pragma unroll
    for (int b = 0; b < B; ++b) up[b] = 0.f;
    const float* wrow = W1 + (size_t)(n * 64) * H + h;
    for (int j = 0; j < 64; ++j) {
        float wv = wrow[(size_t)j * H];
        p += wv;
#pragma unroll
        for (int b = 0; b < B; ++b) up[b] += wv * xs[b][j];
    }
    ws[OFF_P + n * H + h] = p;
    for (int b = 0; b < B; ++b) ws[OFF_UPART + (n * B + b) * H + h] = up[b];
}

// K2: per-sample: u -> t,s,st2 ; c ; q ; ||v||
__global__ void k2_sample(const float* __restrict__ W2,
                          const float* __restrict__ state,
                          float* __restrict__ ws) {
    int b = blockIdx.x;       // 0..7
    int h = threadIdx.x;      // 0..511
    __shared__ float red[512 * 8];
    __shared__ float msh[8];

    float u = 0.f, c = 0.f;
    for (int n = 0; n < NCH; ++n) {
        u += ws[OFF_UPART + (n * B + b) * H + h];
        c += ws[OFF_P + n * H + h];
    }
    float tt  = tanhf(u);
    float s   = 1.f - tt * tt;
    float st2 = -2.f * tt * s;
    ws[OFF_S   + b * H + h] = s;
    ws[OFF_ST2 + b * H + h] = st2;
    ws[OFF_C   + h] = c;                    // identical across blocks — benign

    float w2r[8];
#pragma unroll
    for (int o = 0; o < 8; ++o) w2r[o] = W2[h * 8 + o];

    float cs = c * s;
#pragma unroll
    for (int o = 0; o < 8; ++o) red[h * 8 + o] = cs * w2r[o];
    __syncthreads();
    for (int stp = 256; stp > 0; stp >>= 1) {
        if (h < stp) {
#pragma unroll
            for (int o = 0; o < 8; ++o) red[h * 8 + o] += red[(h + stp) * 8 + o];
        }
        __syncthreads();
    }
    if (h < 8) msh[h] = red[h];
    __syncthreads();
    float q = 0.f;
#pragma unroll
    for (int o = 0; o < 8; ++o) q += w2r[o] * msh[o];
    ws[OFF_Q + b * H + h] = q;

    // ||v_b||
    float sq = 0.f;
    const float* v = state + (size_t)(B + b) * D;
    for (int j = 0; j < D / H; ++j) { float vv = v[j * H + h]; sq += vv * vv; }
    __syncthreads();
    red[h] = sq;
    __syncthreads();
    for (int stp = 256; stp > 0; stp >>= 1) {
        if (h < stp) red[h] += red[h + stp];
        __syncthreads();
    }
    if (h == 0) ws[OFF_VN + b] = sqrtf(red[0]) + 1e-6f;
}

// K3: per (n,b): M[o] = sum_h P*s*W2 ; r = W2@M ; w = st2*(P*q + c*r)
__global__ void k3_w(const float* __restrict__ W2,
                     float* __restrict__ ws) {
    int n = blockIdx.x;   // 0..63
    int b = blockIdx.y;   // 0..7
    int h = threadIdx.x;  // 0..511
    __shared__ float red[512 * 8];
    __shared__ float msh[8];

    float P = ws[OFF_P + n * H + h];
    float s = ws[OFF_S + b * H + h];
    float ps = P * s;
    float w2r[8];
#pragma unroll
    for (int o = 0; o < 8; ++o) w2r[o] = W2[h * 8 + o];
#pragma unroll
    for (int o = 0; o < 8; ++o) red[h * 8 + o] = ps * w2r[o];
    __syncthreads();
    for (int stp = 256; stp > 0; stp >>= 1) {
        if (h < stp) {
#pragma unroll
            for (int o = 0; o < 8; ++o) red[h * 8 + o] += red[(h + stp) * 8 + o];
        }
        __syncthreads();
    }
    if (h < 8) msh[h] = red[h];
    __syncthreads();
    float r = 0.f;
#pragma unroll
    for (int o = 0; o < 8; ++o) r += w2r[o] * msh[o];
    float wv = ws[OFF_ST2 + b * H + h] * (P * ws[OFF_Q + b * H + h] + ws[OFF_C + h] * r);
    ws[OFF_W + ((size_t)(b * NCH + n)) * H + h] = wv;
}

// K4: per (i_t, b): g tile [64n x 64k] = w[b] @ W1[i_t-rows]^T, then norms, y, z-atomics
#define KT 32
__global__ __launch_bounds__(256) void k4_gemm(const float* __restrict__ W1,
                                               const float* __restrict__ state,
                                               float* __restrict__ ws) {
    int it  = blockIdx.x;   // d-tile (=i), 0..63
    int b   = blockIdx.y;   // 0..7
    int tid = threadIdx.x;  // 0..255
    int tx = tid & 15, ty = tid >> 4;

    __shared__ float Ws[KT][68];    // W1 tile, [h][k]
    __shared__ float As[KT][68];    // w  tile, [h][n]
    __shared__ float g_s[64][65];
    __shared__ float vs[D];
    __shared__ float coef_s[64];

    // stage whole v_b row (needed for y and z)
    const float* v = state + (size_t)(B + b) * D;
    for (int r = 0; r < 4; ++r) {
        int idx = tid + r * 256;
        ((float4*)vs)[idx] = ((const float4*)v)[idx];
    }

    float acc[4][4];
#pragma unroll
    for (int i = 0; i < 4; ++i)
#pragma unroll
        for (int j = 0; j < 4; ++j) acc[i][j] = 0.f;

    const float* wbase  = ws + OFF_W + (size_t)(b * NCH) * H;  // [n][h]
    const float* w1base = W1 + (size_t)(it * 64) * H;          // [k][h]

    int lrow = tid >> 3;   // 0..31
    int lcol = tid & 7;    // h-group

    for (int kk = 0; kk < H / KT; ++kk) {
        int h0 = kk * KT;
#pragma unroll
        for (int rr = 0; rr < 2; ++rr) {
            int row = lrow + rr * 32;
            float4 wv = *(const float4*)&w1base[(size_t)row * H + h0 + lcol * 4];
            float4 av = *(const float4*)&wbase [(size_t)row * H + h0 + lcol * 4];
            Ws[lcol * 4 + 0][row] = wv.x; Ws[lcol * 4 + 1][row] = wv.y;
            Ws[lcol * 4 + 2][row] = wv.z; Ws[lcol * 4 + 3][row] = wv.w;
            As[lcol * 4 + 0][row] = av.x; As[lcol * 4 + 1][row] = av.y;
            As[lcol * 4 + 2][row] = av.z; As[lcol * 4 + 3][row] = av.w;
        }
        __syncthreads();
#pragma unroll
        for (int hh = 0; hh < KT; ++hh) {
            float4 af = *(const float4*)&As[hh][ty * 4];
            float4 bf = *(const float4*)&Ws[hh][tx * 4];
            acc[0][0] += af.x * bf.x; acc[0][1] += af.x * bf.y; acc[0][2] += af.x * bf.z; acc[0][3] += af.x * bf.w;
            acc[1][0] += af.y * bf.x; acc[1][1] += af.y * bf.y; acc[1][2] += af.y * bf.z; acc[1][3] += af.y * bf.w;
            acc[2][0] += af.z * bf.x; acc[2][1] += af.z * bf.y; acc[2][2] += af.z * bf.z; acc[2][3] += af.z * bf.w;
            acc[3][0] += af.w * bf.x; acc[3][1] += af.w * bf.y; acc[3][2] += af.w * bf.z; acc[3][3] += af.w * bf.w;
        }
        __syncthreads();
    }

#pragma unroll
    for (int i = 0; i < 4; ++i)
#pragma unroll
        for (int j = 0; j < 4; ++j)
            g_s[ty * 4 + i][tx * 4 + j] = acc[i][j];
    __syncthreads();

    if (tid < 64) {
        int n = tid;
        float ss = 0.f, y = 0.f;
        for (int k = 0; k < 64; ++k) {
            float gv = g_s[n][k];
            ss += gv * gv;
            y  += gv * vs[n * 64 + k];
        }
        float nrm = sqrtf(ss) + 1e-6f;
        coef_s[n] = vs[n * 64 + it] / nrm;
        ws[OFF_A1 + (size_t)(b * NCH + n) * CCH + it] = y / nrm;
    }
    __syncthreads();

    float* z = ws + OFF_Z + (size_t)(b * NCH) * CCH;
    for (int r = 0; r < 16; ++r) {
        int idx = tid + r * 256;        // 0..4095
        int n = idx >> 6, k = idx & 63;
        atomicAdd(&z[n * 64 + k], g_s[n][k] * coef_s[n]);
    }
}

// K5: final assembly
__global__ void k5_final(const float* __restrict__ state,
                         const float* __restrict__ ws,
                         float* __restrict__ out) {
    int idx = blockIdx.x * 256 + threadIdx.x;   // 0..32767
    float vel = state[32768 + idx];
    out[idx] = vel;                              // first half: dev_velocity
    int b = idx >> 12;
    float a1 = ws[OFF_A1 + (size_t)b * 4096 + (idx & 4095)];
    float zv = ws[OFF_Z  + (size_t)b * 4096 + (idx & 4095)];
    float av = -0.5f * vel * (a1 + zv) / ws[OFF_VN + b];
    out[32768 + idx] = av - 0.1f * state[idx];   // a/(||v||+eps) - 0.1*dev
}

extern "C" void kernel_launch(void* const* d_in, const int* in_sizes, int n_in,
                              void* d_out, int out_size, void* d_ws, size_t ws_size,
                              hipStream_t stream) {
    const float* t   = (const float*)d_in[0];
    const float* st  = (const float*)d_in[1];
    const float* x0  = (const float*)d_in[2];
    const float* x1  = (const float*)d_in[3];
    const float* W1  = (const float*)d_in[4];
    const float* W2  = (const float*)d_in[5];
    float* out = (float*)d_out;
    float* ws  = (float*)d_ws;

    hipLaunchKernelGGL(k0_zero,      dim3(128),      dim3(256), 0, stream, ws);
    hipLaunchKernelGGL(k1_reduce_w1, dim3(64, 4),    dim3(128), 0, stream, W1, st, x0, x1, t, ws);
    hipLaunchKernelGGL(k2_sample,    dim3(8),        dim3(512), 0, stream, W2, st, ws);
    hipLaunchKernelGGL(k3_w,         dim3(64, 8),    dim3(512), 0, stream, W2, ws);
    hipLaunchKernelGGL(k4_gemm,      dim3(64, 8),    dim3(256), 0, stream, W1, st, ws);
    hipLaunchKernelGGL(k5_final,     dim3(128),      dim3(256), 0, stream, st, ws, out);
}

// Round 2
// 117.722 us; speedup vs baseline: 1.1541x; 1.1541x over previous
//
#include <hip/hip_runtime.h>

#define D 4096
#define H 512
#define NCH 64
#define CCH 64
#define B 8
#define COUT 8

typedef __bf16 bf16x8 __attribute__((ext_vector_type(8)));
typedef float  f32x4  __attribute__((ext_vector_type(4)));

// workspace layout (float offsets), regions 16B-aligned
#define OFF_P    0                         // P[n][h]              32768
#define OFF_UP   (OFF_P + NCH*H)           // upart[n][b][h]       262144
#define OFF_S    (OFF_UP + NCH*B*H)        // s[b][h]              4096
#define OFF_ST2  (OFF_S + B*H)             // -2*t*s[b][h]         4096
#define OFF_Q    (OFF_ST2 + B*H)           // q[b][h]              4096
#define OFF_C    (OFF_Q + B*H)             // c[h]                 512
#define OFF_VN   (OFF_C + H)               // ||v_b||+1e-6         64 (pad)
#define OFF_A1   (OFF_VN + 64)             // a1[b][n*64+i]        32768
#define OFF_ZB   (OFF_A1 + B*NCH*CCH)      // zblk[b][i][n*64+k]   8*64*4096 = 2097152
#define OFF_W1H  (OFF_ZB + B*64*4096)      // W1hi bf16 [d][h]     (2M ushort = 1048576 f)
#define OFF_W1L  (OFF_W1H + (D*H)/2)       // W1lo bf16 [d][h]
#define OFF_WH   (OFF_W1L + (D*H)/2)       // whi bf16 [b][n][h]   (262144 ushort = 131072 f)
#define OFF_WL   (OFF_WH + (B*NCH*H)/2)    // wlo bf16 [b][n][h]

__device__ __forceinline__ unsigned short f2bf(float x) {
    unsigned int u = __float_as_uint(x);
    unsigned int r = (u + 0x7FFFu + ((u >> 16) & 1u)) >> 16;   // RNE
    return (unsigned short)r;
}
__device__ __forceinline__ float bf2f(unsigned short s) {
    return __uint_as_float(((unsigned int)s) << 16);
}

// K1: per (n-chunk, h-tile): P[n,h], upart[n,b,h]; fused W1 -> bf16 hi/lo conversion
__global__ void k1_reduce_w1(const float* __restrict__ W1,
                             const float* __restrict__ state,
                             const float* __restrict__ x0,
                             const float* __restrict__ x1,
                             const float* __restrict__ tptr,
                             float* __restrict__ ws) {
    int n   = blockIdx.x;          // 0..63
    int ht  = blockIdx.y;          // 0..3
    int tid = threadIdx.x;         // 0..127
    int h   = ht * 128 + tid;

    __shared__ float xs[B][64];
    float ts = tptr[0];
    float window = 4.f * ts * (1.f - ts);
    if (tid < 64) {
        int d = n * 64 + tid;
        for (int b = 0; b < B; ++b) {
            float a0 = x0[b * D + d];
            float a1v = x1[b * D + d];
            float dev = state[b * D + d];
            xs[b][tid] = a0 + ts * (a1v - a0) + window * dev;
        }
    }
    __syncthreads();

    unsigned short* __restrict__ W1Hp = (unsigned short*)(ws + OFF_W1H);
    unsigned short* __restrict__ W1Lp = (unsigned short*)(ws + OFF_W1L);

    float p = 0.f;
    float up[B];
#pragma unroll
    for (int b = 0; b < B; ++b) up[b] = 0.f;
    for (int j = 0; j < 64; ++j) {
        int d = n * 64 + j;
        float wv = W1[(size_t)d * H + h];
        unsigned short hi = f2bf(wv);
        W1Hp[d * H + h] = hi;
        W1Lp[d * H + h] = f2bf(wv - bf2f(hi));
        p += wv;
#pragma unroll
        for (int b = 0; b < B; ++b) up[b] += wv * xs[b][j];
    }
    ws[OFF_P + n * H + h] = p;
    for (int b = 0; b < B; ++b) ws[OFF_UP + (n * B + b) * H + h] = up[b];
}

// K2: per-sample: u -> s,st2 ; c ; q ; ||v||  (wave-shuffle reductions)
__global__ void k2_sample(const float* __restrict__ W2,
                          const float* __restrict__ state,
                          float* __restrict__ ws) {
    int b = blockIdx.x, tid = threadIdx.x;     // 512 threads
    int wid = tid >> 6, lane = tid & 63;
    __shared__ float lm[8][8];
    __shared__ float ms[8];
    __shared__ float lv[8];

    int h = tid;
    float u = 0.f, c = 0.f;
    for (int n = 0; n < NCH; ++n) {
        u += ws[OFF_UP + (n * B + b) * H + h];
        c += ws[OFF_P + n * H + h];
    }
    float tt  = tanhf(u);
    float s   = 1.f - tt * tt;
    float st2 = -2.f * tt * s;
    ws[OFF_S   + b * H + h] = s;
    ws[OFF_ST2 + b * H + h] = st2;
    ws[OFF_C   + h] = c;   // same value from every block — benign

    const float4* w2p = (const float4*)(W2 + h * 8);
    float4 w2a = w2p[0], w2b = w2p[1];
    float w2r[8] = {w2a.x, w2a.y, w2a.z, w2a.w, w2b.x, w2b.y, w2b.z, w2b.w};

    float cs = c * s;
    float pr[8];
#pragma unroll
    for (int o = 0; o < 8; ++o) pr[o] = cs * w2r[o];
#pragma unroll
    for (int mk = 1; mk < 64; mk <<= 1)
#pragma unroll
        for (int o = 0; o < 8; ++o) pr[o] += __shfl_xor(pr[o], mk);
    if (lane == 0)
#pragma unroll
        for (int o = 0; o < 8; ++o) lm[wid][o] = pr[o];

    // ||v||^2 partial
    float v2 = 0.f;
    const float* v = state + (size_t)(B + b) * D;
    for (int j = 0; j < D / H; ++j) { float vv = v[j * H + h]; v2 += vv * vv; }
#pragma unroll
    for (int mk = 1; mk < 64; mk <<= 1) v2 += __shfl_xor(v2, mk);
    if (lane == 0) lv[wid] = v2;
    __syncthreads();

    if (tid < 8) {
        float a = 0.f;
        for (int w = 0; w < 8; ++w) a += lm[w][tid];
        ms[tid] = a;
    }
    if (tid == 0) {
        float a = 0.f;
        for (int w = 0; w < 8; ++w) a += lv[w];
        ws[OFF_VN + b] = sqrtf(a) + 1e-6f;
    }
    __syncthreads();

    float q = 0.f;
#pragma unroll
    for (int o = 0; o < 8; ++o) q += w2r[o] * ms[o];
    ws[OFF_Q + b * H + h] = q;
}

// K3: per (n,b): M[o] = sum_h P*s*W2 ; r = W2@M ; w = st2*(P*q + c*r) -> bf16 hi/lo
__global__ void k3_w(const float* __restrict__ W2,
                     float* __restrict__ ws) {
    int n = blockIdx.x, b = blockIdx.y, lane = threadIdx.x;   // 64 threads
    float M[8];
#pragma unroll
    for (int o = 0; o < 8; ++o) M[o] = 0.f;
    for (int j = 0; j < 8; ++j) {
        int h = j * 64 + lane;
        float ps = ws[OFF_P + n * H + h] * ws[OFF_S + b * H + h];
        const float4* wp = (const float4*)(W2 + h * 8);
        float4 wa = wp[0], wb = wp[1];
        M[0] += ps * wa.x; M[1] += ps * wa.y; M[2] += ps * wa.z; M[3] += ps * wa.w;
        M[4] += ps * wb.x; M[5] += ps * wb.y; M[6] += ps * wb.z; M[7] += ps * wb.w;
    }
#pragma unroll
    for (int mk = 1; mk < 64; mk <<= 1)
#pragma unroll
        for (int o = 0; o < 8; ++o) M[o] += __shfl_xor(M[o], mk);

    unsigned short* __restrict__ WHp = (unsigned short*)(ws + OFF_WH);
    unsigned short* __restrict__ WLp = (unsigned short*)(ws + OFF_WL);
    for (int j = 0; j < 8; ++j) {
        int h = j * 64 + lane;
        const float4* wp = (const float4*)(W2 + h * 8);
        float4 wa = wp[0], wb = wp[1];
        float r = wa.x*M[0] + wa.y*M[1] + wa.z*M[2] + wa.w*M[3]
                + wb.x*M[4] + wb.y*M[5] + wb.z*M[6] + wb.w*M[7];
        float P = ws[OFF_P + n * H + h];
        float wv = ws[OFF_ST2 + b * H + h] * (P * ws[OFF_Q + b * H + h] + ws[OFF_C + h] * r);
        unsigned short hi = f2bf(wv);
        WHp[(b * NCH + n) * H + h] = hi;
        WLp[(b * NCH + n) * H + h] = f2bf(wv - bf2f(hi));
    }
}

// K4: per (i, b): G[64n][64k] = w[b] @ W1[i-rows]^T via bf16x3 MFMA, K split over 4 waves.
// Direct-from-L2 fragment loads (no LDS staging, no K-loop barriers).
__global__ __launch_bounds__(256) void k4_mfma(const float* __restrict__ state,
                                               float* __restrict__ ws) {
    int i   = blockIdx.x;   // 0..63
    int b   = blockIdx.y;   // 0..7
    int tid = threadIdx.x;  // 0..255
    int wid = tid >> 6, lane = tid & 63;
    int r16 = lane & 15;
    int kgrp = (lane >> 4) * 8;

    __shared__ float vsp[64][65];
    __shared__ float gp[2][64][67];
    __shared__ float coefs[64];

    // stage v_b as [n][k] with pad
    const float* v = state + (size_t)(B + b) * D;
    for (int r = 0; r < 4; ++r) {
        int fidx = tid + r * 256;                   // float4 index
        float4 val = ((const float4*)v)[fidx];
        int base = fidx * 4, row = base >> 6, col = base & 63;
        vsp[row][col] = val.x; vsp[row][col+1] = val.y;
        vsp[row][col+2] = val.z; vsp[row][col+3] = val.w;
    }

    const unsigned short* __restrict__ W1Hp = (const unsigned short*)(ws + OFF_W1H);
    const unsigned short* __restrict__ W1Lp = (const unsigned short*)(ws + OFF_W1L);
    const unsigned short* __restrict__ WHp  = (const unsigned short*)(ws + OFF_WH);
    const unsigned short* __restrict__ WLp  = (const unsigned short*)(ws + OFF_WL);

    f32x4 acc[4][4];
    f32x4 z4 = {0.f, 0.f, 0.f, 0.f};
#pragma unroll
    for (int m = 0; m < 4; ++m)
#pragma unroll
        for (int c = 0; c < 4; ++c) acc[m][c] = z4;

    int kb = wid * 128 + kgrp;     // this wave's K-quarter base + lane k-group
#pragma unroll
    for (int ks = 0; ks < 4; ++ks) {
        int k = kb + ks * 32;
        bf16x8 ah[4], al[4], bh[4], bl[4];
#pragma unroll
        for (int m = 0; m < 4; ++m) {
            int off = (b * 64 + m * 16 + r16) * H + k;
            ah[m] = *(const bf16x8*)(WHp + off);
            al[m] = *(const bf16x8*)(WLp + off);
        }
#pragma unroll
        for (int c = 0; c < 4; ++c) {
            int off = (i * 64 + c * 16 + r16) * H + k;
            bh[c] = *(const bf16x8*)(W1Hp + off);
            bl[c] = *(const bf16x8*)(W1Lp + off);
        }
#pragma unroll
        for (int m = 0; m < 4; ++m)
#pragma unroll
            for (int c = 0; c < 4; ++c) {
                acc[m][c] = __builtin_amdgcn_mfma_f32_16x16x32_bf16(ah[m], bh[c], acc[m][c], 0, 0, 0);
                acc[m][c] = __builtin_amdgcn_mfma_f32_16x16x32_bf16(ah[m], bl[c], acc[m][c], 0, 0, 0);
                acc[m][c] = __builtin_amdgcn_mfma_f32_16x16x32_bf16(al[m], bh[c], acc[m][c], 0, 0, 0);
            }
    }

    // cross-wave K reduction: waves 0,1 write buffers; waves 2,3 accumulate
    int rowb = (lane >> 4) * 4;
    if (wid < 2) {
        float (*g)[67] = gp[wid];
#pragma unroll
        for (int m = 0; m < 4; ++m)
#pragma unroll
            for (int c = 0; c < 4; ++c)
#pragma unroll
                for (int e = 0; e < 4; ++e)
                    g[m * 16 + rowb + e][c * 16 + r16] = acc[m][c][e];
    }
    __syncthreads();
    if (wid >= 2) {
        float (*g)[67] = gp[wid - 2];
#pragma unroll
        for (int m = 0; m < 4; ++m)
#pragma unroll
            for (int c = 0; c < 4; ++c)
#pragma unroll
                for (int e = 0; e < 4; ++e)
                    g[m * 16 + rowb + e][c * 16 + r16] += acc[m][c][e];
    }
    __syncthreads();

    // epilogue A: per-row norm, y, coef  (lane n = tid)
    if (tid < 64) {
        int n = tid;
        float ss = 0.f, y = 0.f;
        for (int k = 0; k < 64; ++k) {
            float g = gp[0][n][k] + gp[1][n][k];
            ss += g * g;
            y  += g * vsp[n][k];
        }
        float nrm = sqrtf(ss) + 1e-6f;
        ws[OFF_A1 + (size_t)(b * NCH + n) * CCH + i] = y / nrm;
        coefs[n] = vsp[n][i] / nrm;
    }
    __syncthreads();

    // epilogue B: z partial for this i (deterministic, no atomics)
    float* zb = ws + OFF_ZB + ((size_t)b * 64 + i) * 4096;
    for (int r = 0; r < 16; ++r) {
        int idx = tid + r * 256;
        int n = idx >> 6, k = idx & 63;
        zb[idx] = (gp[0][n][k] + gp[1][n][k]) * coefs[n];
    }
}

// K5: reduce z partials over i, final assembly
__global__ void k5_final(const float* __restrict__ state,
                         const float* __restrict__ ws,
                         float* __restrict__ out) {
    int idx = blockIdx.x * 256 + threadIdx.x;   // 0..32767
    float vel = state[32768 + idx];
    out[idx] = vel;
    int b = idx >> 12, e = idx & 4095;
    const float* zb = ws + OFF_ZB + (size_t)b * 64 * 4096 + e;
    float z = 0.f;
    for (int i = 0; i < 64; ++i) z += zb[(size_t)i * 4096];
    float a1 = ws[OFF_A1 + (size_t)b * 4096 + e];
    float av = -0.5f * vel * (a1 + z) / ws[OFF_VN + b];
    out[32768 + idx] = av - 0.1f * state[idx];
}

extern "C" void kernel_launch(void* const* d_in, const int* in_sizes, int n_in,
                              void* d_out, int out_size, void* d_ws, size_t ws_size,
                              hipStream_t stream) {
    const float* t   = (const float*)d_in[0];
    const float* st  = (const float*)d_in[1];
    const float* x0  = (const float*)d_in[2];
    const float* x1  = (const float*)d_in[3];
    const float* W1  = (const float*)d_in[4];
    const float* W2  = (const float*)d_in[5];
    float* out = (float*)d_out;
    float* ws  = (float*)d_ws;

    hipLaunchKernelGGL(k1_reduce_w1, dim3(64, 4), dim3(128), 0, stream, W1, st, x0, x1, t, ws);
    hipLaunchKernelGGL(k2_sample,    dim3(8),     dim3(512), 0, stream, W2, st, ws);
    hipLaunchKernelGGL(k3_w,         dim3(64, 8), dim3(64),  0, stream, W2, ws);
    hipLaunchKernelGGL(k4_mfma,      dim3(64, 8), dim3(256), 0, stream, st, ws);
    hipLaunchKernelGGL(k5_final,     dim3(128),   dim3(256), 0, stream, st, ws, out);
}